// Round 1
// baseline (275.057 us; speedup 1.0000x reference)
//
#include <hip/hip_runtime.h>
#include <cstdint>
#include <cstddef>

// ---------- types ----------
typedef __bf16 bf16;
typedef bf16  bf16x4  __attribute__((ext_vector_type(4)));
typedef bf16  bf16x8  __attribute__((ext_vector_type(8)));
typedef float floatx4 __attribute__((ext_vector_type(4)));

// Problem constants (reference: B=2, S=2048, D=1024, H=16, Dh=64)
#define BATCH 2
#define SEQ   2048
#define DIM   1024
#define NH    16
#define DH    64
#define D3    3072
#define MROWS 4096   // BATCH*SEQ

// async global->LDS, 16B per lane; LDS dest must be wave-uniform base + lane*16
__device__ __forceinline__ void gld16(void* lds, const void* gptr) {
  __builtin_amdgcn_global_load_lds(
      (const __attribute__((address_space(1))) unsigned int*)gptr,
      (__attribute__((address_space(3))) unsigned int*)lds, 16, 0, 0);
}

// ---------- kernel 1: fp32 -> bf16 convert (x) ----------
__global__ __launch_bounds__(256) void k_convert_x(const float4* __restrict__ in,
                                                   bf16* __restrict__ out) {
  int i = blockIdx.x * 256 + threadIdx.x;     // 1048576 float4s total
  float4 v = in[i];
  bf16x4 o;
  o.x = (bf16)v.x; o.y = (bf16)v.y; o.z = (bf16)v.z; o.w = (bf16)v.w;
  *(bf16x4*)(out + (size_t)i * 4) = o;
}

// ---------- kernel 2: W[K][N] fp32 -> Wt[N][K] bf16 (32x32 LDS tiles) ----------
__global__ __launch_bounds__(256) void k_transpose_w(const float* __restrict__ W,
                                                     bf16* __restrict__ Wt,
                                                     int K, int N) {
  __shared__ float tile[32][33];
  int k0 = blockIdx.y * 32, n0 = blockIdx.x * 32;
  int tx = threadIdx.x & 31, ty = threadIdx.x >> 5;   // ty in [0,8)
#pragma unroll
  for (int i = 0; i < 4; i++)
    tile[ty + i * 8][tx] = W[(size_t)(k0 + ty + i * 8) * N + n0 + tx];
  __syncthreads();
#pragma unroll
  for (int i = 0; i < 4; i++)
    Wt[(size_t)(n0 + ty + i * 8) * K + k0 + tx] = (bf16)tile[tx][ty + i * 8];
}

// ---------- kernel 3: GEMM  C[M][N] = A[M][K] * Bt[N][K]^T  (m97 structure) ----------
// 128x128 tile, BK=32, 4 waves (each 64x64), 16x16x32 bf16 MFMA.
template <typename OutT>
__global__ __launch_bounds__(256) void k_gemm_bt(const bf16* __restrict__ A,
                                                 const bf16* __restrict__ Bt,
                                                 OutT* __restrict__ C,
                                                 int M, int N, int K) {
  __shared__ __align__(16) bf16 As[128 * 32];
  __shared__ __align__(16) bf16 Bs[128 * 32];
  const int t = threadIdx.x, l = t & 63, w = t >> 6;
  const int wr = w >> 1, wc = w & 1;
  const int q = l >> 4, mm = l & 15;
  const int m0 = blockIdx.y * 128, n0 = blockIdx.x * 128;

  floatx4 acc[4][4] = {};

  for (int kt = 0; kt < K; kt += 32) {
    __syncthreads();                       // prior iter's LDS reads done
#pragma unroll
    for (int i = 0; i < 2; i++) {
      int c = t + i * 256;                 // 512 chunks of 16B per tile
      int row = c >> 2, col = (c & 3) * 8;
      gld16((char*)As + (size_t)c * 16, A  + (size_t)(m0 + row) * K + kt + col);
      gld16((char*)Bs + (size_t)c * 16, Bt + (size_t)(n0 + row) * K + kt + col);
    }
    __syncthreads();                       // drains vmcnt: staging complete
    bf16x8 af[4], bfr[4];
#pragma unroll
    for (int mt = 0; mt < 4; mt++)
      af[mt] = *(const bf16x8*)(As + (size_t)(wr * 64 + mt * 16 + mm) * 32 + q * 8);
#pragma unroll
    for (int nt = 0; nt < 4; nt++)
      bfr[nt] = *(const bf16x8*)(Bs + (size_t)(wc * 64 + nt * 16 + mm) * 32 + q * 8);
#pragma unroll
    for (int mt = 0; mt < 4; mt++)
#pragma unroll
      for (int nt = 0; nt < 4; nt++)
        acc[mt][nt] = __builtin_amdgcn_mfma_f32_16x16x32_bf16(af[mt], bfr[nt],
                                                              acc[mt][nt], 0, 0, 0);
  }
  // epilogue: C/D layout col=lane&15, row=(lane>>4)*4+reg
#pragma unroll
  for (int mt = 0; mt < 4; mt++)
#pragma unroll
    for (int nt = 0; nt < 4; nt++)
#pragma unroll
      for (int r = 0; r < 4; r++) {
        int row = m0 + wr * 64 + mt * 16 + q * 4 + r;
        int col = n0 + wc * 64 + nt * 16 + mm;
        C[(size_t)row * N + col] = (OutT)acc[mt][nt][r];
      }
}

// ---------- kernel 4: causal flash attention ----------
// grid: 1024 blocks = (b,h) x 32 q-tiles of 64 rows; 4 waves, wave w owns rows w*16..w*16+15.
__global__ __launch_bounds__(256) void k_attn(const bf16* __restrict__ qkv,
                                              bf16* __restrict__ out) {
  const int bx = blockIdx.x;
  const int qt = bx & 31, bh = bx >> 5;
  const int b = bh >> 4, h = bh & 15;
  const int t = threadIdx.x, l = t & 63, w = t >> 6;
  const int q4 = l >> 4, mm = l & 15;

  __shared__ __align__(16) bf16 Qs[2][64][32];   // [kstep][row][k]
  __shared__ __align__(16) bf16 Ks[2][64][32];
  __shared__ __align__(16) bf16 Vt[64][72];      // V^T [dh][s], padded (+8 keeps 16B align)
  __shared__ __align__(16) bf16 Ps[4][16][72];   // per-wave P tile, padded

  const size_t rowbase = (size_t)b * SEQ * D3;

  { // stage Q tile once
    int row = t >> 2, col = (t & 3) * 8;
#pragma unroll
    for (int i = 0; i < 2; i++)
      gld16((char*)(&Qs[i][0][0]) + (size_t)t * 16,
            qkv + rowbase + (size_t)(qt * 64 + row) * D3 + h * 64 + i * 32 + col);
  }
  __syncthreads();
  bf16x8 qf[2];
  qf[0] = *(const bf16x8*)(&Qs[0][w * 16 + mm][q4 * 8]);
  qf[1] = *(const bf16x8*)(&Qs[1][w * 16 + mm][q4 * 8]);

  float m_i[4], l_i[4];
  floatx4 oacc[4];
#pragma unroll
  for (int r = 0; r < 4; r++) { m_i[r] = -__builtin_inff(); l_i[r] = 0.f; }
#pragma unroll
  for (int nt = 0; nt < 4; nt++) { floatx4 z = {0.f, 0.f, 0.f, 0.f}; oacc[nt] = z; }

  const int qrow0 = qt * 64 + w * 16 + q4 * 4;

  for (int kt = 0; kt <= qt; kt++) {
    __syncthreads();                         // prior iter done with Ks/Vt
    { // stage K tile (async) + V tile transposed (manual)
      int row = t >> 2, col = (t & 3) * 8;
#pragma unroll
      for (int i = 0; i < 2; i++)
        gld16((char*)(&Ks[i][0][0]) + (size_t)t * 16,
              qkv + rowbase + (size_t)(kt * 64 + row) * D3 + 1024 + h * 64 + i * 32 + col);
      int s = l;
#pragma unroll
      for (int i = 0; i < 2; i++) {
        int cc = w + i * 4;                   // 8 chunks of 8 dh-elems
        bf16x8 v8 = *(const bf16x8*)(qkv + rowbase + (size_t)(kt * 64 + s) * D3 +
                                     2048 + h * 64 + cc * 8);
#pragma unroll
        for (int e = 0; e < 8; e++) Vt[cc * 8 + e][s] = v8[e];
      }
    }
    __syncthreads();

    // S = Q K^T  (per wave: 16 q-rows x 64 k-cols)
    floatx4 sacc[4];
#pragma unroll
    for (int ct = 0; ct < 4; ct++) { floatx4 z = {0.f, 0.f, 0.f, 0.f}; sacc[ct] = z; }
#pragma unroll
    for (int ks = 0; ks < 2; ks++)
#pragma unroll
      for (int ct = 0; ct < 4; ct++) {
        bf16x8 kf = *(const bf16x8*)(&Ks[ks][ct * 16 + mm][q4 * 8]);
        sacc[ct] = __builtin_amdgcn_mfma_f32_16x16x32_bf16(qf[ks], kf, sacc[ct], 0, 0, 0);
      }

    // scale + causal mask + online softmax
    float p[4][4], mx[4];
#pragma unroll
    for (int r = 0; r < 4; r++) mx[r] = -__builtin_inff();
#pragma unroll
    for (int ct = 0; ct < 4; ct++) {
      int kcol = kt * 64 + ct * 16 + mm;
#pragma unroll
      for (int r = 0; r < 4; r++) {
        float sv = sacc[ct][r] * 0.125f;                 // 1/sqrt(64)
        if (kcol > qrow0 + r) sv = -__builtin_inff();
        p[ct][r] = sv;
        mx[r] = fmaxf(mx[r], sv);
      }
    }
#pragma unroll
    for (int off = 1; off < 16; off <<= 1)
#pragma unroll
      for (int r = 0; r < 4; r++)
        mx[r] = fmaxf(mx[r], __shfl_xor(mx[r], off, 64));

    float alpha[4];
#pragma unroll
    for (int r = 0; r < 4; r++) {
      float mnew = fmaxf(m_i[r], mx[r]);
      alpha[r] = __expf(m_i[r] - mnew);                  // exp(-inf - finite) = 0
      m_i[r] = mnew;
    }
    float rsum[4] = {0.f, 0.f, 0.f, 0.f};
#pragma unroll
    for (int ct = 0; ct < 4; ct++)
#pragma unroll
      for (int r = 0; r < 4; r++) {
        float e = __expf(p[ct][r] - m_i[r]);
        p[ct][r] = e;
        rsum[r] += e;
      }
#pragma unroll
    for (int off = 1; off < 16; off <<= 1)
#pragma unroll
      for (int r = 0; r < 4; r++)
        rsum[r] += __shfl_xor(rsum[r], off, 64);
#pragma unroll
    for (int r = 0; r < 4; r++) l_i[r] = l_i[r] * alpha[r] + rsum[r];
#pragma unroll
    for (int nt = 0; nt < 4; nt++)
#pragma unroll
      for (int r = 0; r < 4; r++) oacc[nt][r] *= alpha[r];

    // P: C-layout -> A-layout via per-wave LDS (in-order DS pipe within a wave)
#pragma unroll
    for (int ct = 0; ct < 4; ct++)
#pragma unroll
      for (int r = 0; r < 4; r++)
        Ps[w][q4 * 4 + r][ct * 16 + mm] = (bf16)p[ct][r];

    // O += P V
#pragma unroll
    for (int ks = 0; ks < 2; ks++) {
      bf16x8 pf = *(const bf16x8*)(&Ps[w][mm][ks * 32 + q4 * 8]);
#pragma unroll
      for (int nt = 0; nt < 4; nt++) {
        bf16x8 vf = *(const bf16x8*)(&Vt[nt * 16 + mm][ks * 32 + q4 * 8]);
        oacc[nt] = __builtin_amdgcn_mfma_f32_16x16x32_bf16(pf, vf, oacc[nt], 0, 0, 0);
      }
    }
  }

  // epilogue: normalize and store bf16 [4096][1024]
#pragma unroll
  for (int nt = 0; nt < 4; nt++)
#pragma unroll
    for (int r = 0; r < 4; r++) {
      int row = qt * 64 + w * 16 + q4 * 4 + r;
      int col = h * 64 + nt * 16 + mm;
      out[((size_t)b * SEQ + row) * DIM + col] = (bf16)(oacc[nt][r] / l_i[r]);
    }
}

// ---------- launch ----------
extern "C" void kernel_launch(void* const* d_in, const int* in_sizes, int n_in,
                              void* d_out, int out_size, void* d_ws, size_t ws_size,
                              hipStream_t stream) {
  const float* x     = (const float*)d_in[0];   // [2,2048,1024]
  const float* W_in  = (const float*)d_in[1];   // [1024,3072]
  const float* W_out = (const float*)d_in[2];   // [1024,1024]
  float* out = (float*)d_out;                   // [2,2048,1024]

  char* ws = (char*)d_ws;
  bf16* xb   = (bf16*)(ws);                       //  8 MB: x bf16 [4096][1024]
  bf16* wti  = (bf16*)(ws + 8388608);             //  6 MB: W_in^T  [3072][1024]
  bf16* wto  = (bf16*)(ws + 14680064);            //  2 MB: W_out^T [1024][1024]
  bf16* qkv  = (bf16*)(ws + 16777216);            // 24 MB: qkv bf16 [4096][3072]
  bf16* attn = xb;                                //  reuse: xb dead after GEMM1

  k_convert_x<<<4096, 256, 0, stream>>>((const float4*)x, xb);
  k_transpose_w<<<dim3(96, 32), 256, 0, stream>>>(W_in, wti, 1024, 3072);
  k_transpose_w<<<dim3(32, 32), 256, 0, stream>>>(W_out, wto, 1024, 1024);
  k_gemm_bt<bf16><<<dim3(24, 32), 256, 0, stream>>>(xb, wti, qkv, MROWS, D3, DIM);
  k_attn<<<1024, 256, 0, stream>>>(qkv, attn);
  k_gemm_bt<float><<<dim3(8, 32), 256, 0, stream>>>(attn, wto, out, MROWS, DIM, DIM);
}

// Round 2
// 219.198 us; speedup vs baseline: 1.2548x; 1.2548x over previous
//
#include <hip/hip_runtime.h>
#include <cstdint>
#include <cstddef>

// ---------- types ----------
typedef __bf16 bf16;
typedef bf16  bf16x4  __attribute__((ext_vector_type(4)));
typedef bf16  bf16x8  __attribute__((ext_vector_type(8)));
typedef float floatx4 __attribute__((ext_vector_type(4)));

// Problem constants (reference: B=2, S=2048, D=1024, H=16, Dh=64)
#define BATCH 2
#define SEQ   2048
#define DIM   1024
#define NH    16
#define DH    64
#define D3    3072
#define MROWS 4096   // BATCH*SEQ

// async global->LDS, 16B per lane; LDS dest must be wave-uniform base + lane*16
__device__ __forceinline__ void gld16(void* lds, const void* gptr) {
  __builtin_amdgcn_global_load_lds(
      (const __attribute__((address_space(1))) unsigned int*)gptr,
      (__attribute__((address_space(3))) unsigned int*)lds, 16, 0, 0);
}

// ---------- kernel 1: fp32 -> bf16 convert (x) ----------
__global__ __launch_bounds__(256) void k_convert_x(const float4* __restrict__ in,
                                                   bf16* __restrict__ out) {
  int i = blockIdx.x * 256 + threadIdx.x;     // 1048576 float4s total
  float4 v = in[i];
  bf16x4 o;
  o.x = (bf16)v.x; o.y = (bf16)v.y; o.z = (bf16)v.z; o.w = (bf16)v.w;
  *(bf16x4*)(out + (size_t)i * 4) = o;
}

// ---------- kernel 2: W[K][N] fp32 -> Wt[N][K] bf16 (32x32 LDS tiles) ----------
__global__ __launch_bounds__(256) void k_transpose_w(const float* __restrict__ W,
                                                     bf16* __restrict__ Wt,
                                                     int K, int N) {
  __shared__ float tile[32][33];
  int k0 = blockIdx.y * 32, n0 = blockIdx.x * 32;
  int tx = threadIdx.x & 31, ty = threadIdx.x >> 5;   // ty in [0,8)
#pragma unroll
  for (int i = 0; i < 4; i++)
    tile[ty + i * 8][tx] = W[(size_t)(k0 + ty + i * 8) * N + n0 + tx];
  __syncthreads();
#pragma unroll
  for (int i = 0; i < 4; i++)
    Wt[(size_t)(n0 + ty + i * 8) * K + k0 + tx] = (bf16)tile[tx][ty + i * 8];
}

// ---------- kernel 3: GEMM  C = A[M][K] * Bt[N][K]^T  (m97 structure) ----------
// MODE 0: plain C[M][N] (OutT). MODE 1: qkv-split epilogue:
//   cols <2048 -> qk[row][col] (stride 2048); cols >=2048 -> vt[bh*64+dh][s] (V transposed)
template <typename OutT, int MODE>
__global__ __launch_bounds__(256) void k_gemm_bt(const bf16* __restrict__ A,
                                                 const bf16* __restrict__ Bt,
                                                 OutT* __restrict__ C,
                                                 bf16* __restrict__ qk,
                                                 bf16* __restrict__ vt,
                                                 int M, int N, int K) {
  __shared__ __align__(16) bf16 As[128 * 32];
  __shared__ __align__(16) bf16 Bs[128 * 32];
  const int t = threadIdx.x, l = t & 63, w = t >> 6;
  const int wr = w >> 1, wc = w & 1;
  const int q = l >> 4, mm = l & 15;
  const int m0 = blockIdx.y * 128, n0 = blockIdx.x * 128;

  floatx4 acc[4][4] = {};

  for (int kt = 0; kt < K; kt += 32) {
    __syncthreads();
#pragma unroll
    for (int i = 0; i < 2; i++) {
      int c = t + i * 256;                 // 512 chunks of 16B per tile
      int row = c >> 2, col = (c & 3) * 8;
      gld16((char*)As + (size_t)c * 16, A  + (size_t)(m0 + row) * K + kt + col);
      gld16((char*)Bs + (size_t)c * 16, Bt + (size_t)(n0 + row) * K + kt + col);
    }
    __syncthreads();
    bf16x8 af[4], bfr[4];
#pragma unroll
    for (int mt = 0; mt < 4; mt++)
      af[mt] = *(const bf16x8*)(As + (size_t)(wr * 64 + mt * 16 + mm) * 32 + q * 8);
#pragma unroll
    for (int nt = 0; nt < 4; nt++)
      bfr[nt] = *(const bf16x8*)(Bs + (size_t)(wc * 64 + nt * 16 + mm) * 32 + q * 8);
#pragma unroll
    for (int mt = 0; mt < 4; mt++)
#pragma unroll
      for (int nt = 0; nt < 4; nt++)
        acc[mt][nt] = __builtin_amdgcn_mfma_f32_16x16x32_bf16(af[mt], bfr[nt],
                                                              acc[mt][nt], 0, 0, 0);
  }
  // epilogue: C/D layout col=lane&15, row=(lane>>4)*4+reg
#pragma unroll
  for (int mt = 0; mt < 4; mt++)
#pragma unroll
    for (int nt = 0; nt < 4; nt++)
#pragma unroll
      for (int r = 0; r < 4; r++) {
        int row = m0 + wr * 64 + mt * 16 + q * 4 + r;
        int col = n0 + wc * 64 + nt * 16 + mm;
        if (MODE == 0) {
          C[(size_t)row * N + col] = (OutT)acc[mt][nt][r];
        } else {
          if (n0 < 2048) {
            qk[(size_t)row * 2048 + col] = (bf16)acc[mt][nt][r];
          } else {
            int d = col - 2048;                  // 0..1023
            int hh = d >> 6, dh = d & 63;
            int bb = row >> 11, s = row & 2047;
            vt[((size_t)(bb * 16 + hh) * 64 + dh) * SEQ + s] = (bf16)acc[mt][nt][r];
          }
        }
      }
}

// ---------- kernel 4: causal flash attention (transposed dataflow) ----------
// 1024 blocks = (b,h) x 32 q-tiles of 64 rows; 4 waves, wave w owns q rows w*16..w*16+15.
// S^T = mfma(K,Q): lane owns q-row = lane&15; O^T = mfma(V^T, P): lane col = q-row.
__global__ __launch_bounds__(256) void k_attn(const bf16* __restrict__ qk,
                                              const bf16* __restrict__ vt,
                                              bf16* __restrict__ out) {
  const int bx = blockIdx.x;
  const int qt = bx & 31, bh = bx >> 5;
  const int b = bh >> 4, h = bh & 15;
  const int t = threadIdx.x, l = t & 63, w = t >> 6;
  const int q4 = l >> 4, mm = l & 15;

  // LDS: union{ Qs[2][64][32] (8192B, dead after qf load) ; Ps[4][16][72] (9216B) }
  //      Ks[2][64][32] (8192B) ; Vt[64][64] (8192B, XOR-swizzled chunks)
  __shared__ __align__(16) char lds[9216 + 8192 + 8192];
  bf16* Qs = (bf16*)lds;                  // [2][64][32]
  bf16* Ps = (bf16*)lds;                  // [4][16][72]
  bf16* Ks = (bf16*)(lds + 9216);         // [2][64][32]
  bf16* Vs = (bf16*)(lds + 9216 + 8192);  // [64][64], chunk c holds global chunk c^(row&7)

  const size_t qkbase = (size_t)b * SEQ * 2048;
  const size_t vtbase = (size_t)bh * 64 * SEQ;

  { // stage Q tile once (cols h*64 .. h*64+63, rows qt*64..+63)
    int row = t >> 2, col = (t & 3) * 8;
#pragma unroll
    for (int i = 0; i < 2; i++)
      gld16((char*)Qs + ((size_t)t + i * 256) * 16,
            qk + qkbase + (size_t)(qt * 64 + row) * 2048 + h * 64 + i * 32 + col);
  }
  __syncthreads();
  bf16x8 qf[2];
  qf[0] = *(const bf16x8*)(Qs + (size_t)(0 * 64 + w * 16 + mm) * 32 + q4 * 8);
  qf[1] = *(const bf16x8*)(Qs + (size_t)(1 * 64 + w * 16 + mm) * 32 + q4 * 8);
#pragma unroll
  for (int i = 0; i < 2; i++)
#pragma unroll
    for (int j = 0; j < 8; j++)
      qf[i][j] = (bf16)((float)qf[i][j] * 0.125f);   // 1/sqrt(64), exact in bf16

  float m_i = -__builtin_inff(), l_i = 0.f;
  floatx4 oaccT[4];                        // O^T: d = nt*16+q4*4+r, q-col = mm
#pragma unroll
  for (int nt = 0; nt < 4; nt++) { floatx4 z = {0.f, 0.f, 0.f, 0.f}; oaccT[nt] = z; }

  const int qrow = qt * 64 + w * 16 + mm;  // this lane's q row
  const int qloc = w * 16 + mm;            // within-tile

  for (int kt = 0; kt <= qt; kt++) {
    __syncthreads();                       // prior iter done with Ks/Vs
    { // stage K (2x gld16) + V^T (2x gld16, XOR-swizzled 16B chunks)
      int row = t >> 2, col = (t & 3) * 8;
#pragma unroll
      for (int i = 0; i < 2; i++)
        gld16((char*)Ks + ((size_t)t + i * 256) * 16,
              qk + qkbase + (size_t)(kt * 64 + row) * 2048 + 1024 + h * 64 + i * 32 + col);
#pragma unroll
      for (int i = 0; i < 2; i++) {
        int c = t + i * 256;               // 512 chunks: row d = c>>3, chunk cc = c&7
        int rr = c >> 3, cc = c & 7;
        int src = cc ^ (rr & 7);
        gld16((char*)Vs + (size_t)c * 16,
              vt + vtbase + (size_t)rr * SEQ + kt * 64 + src * 8);
      }
    }
    __syncthreads();

    // S^T tile: 64 k rows x 16 q cols per wave: mfma(A=K, B=Q)
    floatx4 sacc[4];
#pragma unroll
    for (int ct = 0; ct < 4; ct++) { floatx4 z = {0.f, 0.f, 0.f, 0.f}; sacc[ct] = z; }
#pragma unroll
    for (int ks = 0; ks < 2; ks++)
#pragma unroll
      for (int ct = 0; ct < 4; ct++) {
        bf16x8 kf = *(const bf16x8*)(Ks + (size_t)(ks * 64 + ct * 16 + mm) * 32 + q4 * 8);
        sacc[ct] = __builtin_amdgcn_mfma_f32_16x16x32_bf16(kf, qf[ks], sacc[ct], 0, 0, 0);
      }

    // per-lane: 16 scores for q=qrow at k = kt*64 + ct*16 + q4*4 + r
    float p[4][4];
    float mx = -__builtin_inff();
    if (kt == qt) {                        // diagonal tile: causal mask
#pragma unroll
      for (int ct = 0; ct < 4; ct++)
#pragma unroll
        for (int r = 0; r < 4; r++) {
          float sv = sacc[ct][r];
          if (ct * 16 + q4 * 4 + r > qloc) sv = -__builtin_inff();
          p[ct][r] = sv;
          mx = fmaxf(mx, sv);
        }
    } else {
#pragma unroll
      for (int ct = 0; ct < 4; ct++)
#pragma unroll
        for (int r = 0; r < 4; r++) {
          p[ct][r] = sacc[ct][r];
          mx = fmaxf(mx, sacc[ct][r]);
        }
    }
    mx = fmaxf(mx, __shfl_xor(mx, 16, 64));
    mx = fmaxf(mx, __shfl_xor(mx, 32, 64));

    float mnew = fmaxf(m_i, mx);
    float alpha = __expf(m_i - mnew);      // exp(-inf - finite) = 0
    m_i = mnew;
    float rsum = 0.f;
#pragma unroll
    for (int ct = 0; ct < 4; ct++)
#pragma unroll
      for (int r = 0; r < 4; r++) {
        float e = __expf(p[ct][r] - m_i);
        p[ct][r] = e;
        rsum += e;
      }
    rsum += __shfl_xor(rsum, 16, 64);
    rsum += __shfl_xor(rsum, 32, 64);
    l_i = l_i * alpha + rsum;
#pragma unroll
    for (int nt = 0; nt < 4; nt++)
#pragma unroll
      for (int r = 0; r < 4; r++) oaccT[nt][r] *= alpha;

    // P^T (C-layout) -> A/B-layout: lane writes its 4 consecutive k per ct (b64 stores)
#pragma unroll
    for (int ct = 0; ct < 4; ct++) {
      bf16x4 pk;
#pragma unroll
      for (int r = 0; r < 4; r++) pk[r] = (bf16)p[ct][r];
      *(bf16x4*)(Ps + (size_t)(w * 16 + mm) * 72 + ct * 16 + q4 * 4) = pk;
    }

    // O^T += mfma(A=V^T, B=P)
#pragma unroll
    for (int ks = 0; ks < 2; ks++) {
      bf16x8 pf = *(const bf16x8*)(Ps + (size_t)(w * 16 + mm) * 72 + ks * 32 + q4 * 8);
#pragma unroll
      for (int nt = 0; nt < 4; nt++) {
        int d = nt * 16 + mm;
        int chunk = (ks * 4 + q4) ^ (d & 7);     // undo staging swizzle
        bf16x8 vf = *(const bf16x8*)(Vs + (size_t)d * 64 + chunk * 8);
        oaccT[nt] = __builtin_amdgcn_mfma_f32_16x16x32_bf16(vf, pf, oaccT[nt], 0, 0, 0);
      }
    }
  }

  // epilogue: lane owns one q row; normalize and store 4x bf16x4
  float inv = 1.0f / l_i;
  bf16* orow = out + ((size_t)b * SEQ + qrow) * DIM + h * 64;
#pragma unroll
  for (int nt = 0; nt < 4; nt++) {
    bf16x4 o4;
#pragma unroll
    for (int r = 0; r < 4; r++) o4[r] = (bf16)(oaccT[nt][r] * inv);
    *(bf16x4*)(orow + nt * 16 + q4 * 4) = o4;
  }
}

// ---------- launch ----------
extern "C" void kernel_launch(void* const* d_in, const int* in_sizes, int n_in,
                              void* d_out, int out_size, void* d_ws, size_t ws_size,
                              hipStream_t stream) {
  const float* x     = (const float*)d_in[0];   // [2,2048,1024]
  const float* W_in  = (const float*)d_in[1];   // [1024,3072]
  const float* W_out = (const float*)d_in[2];   // [1024,1024]
  float* out = (float*)d_out;                   // [2,2048,1024]

  char* ws = (char*)d_ws;
  bf16* xb   = (bf16*)(ws);                       //  8 MB: x bf16 [4096][1024] (reused: attn out)
  bf16* wti  = (bf16*)(ws + 8388608);             //  6 MB: W_in^T  [3072][1024]
  bf16* wto  = (bf16*)(ws + 14680064);            //  2 MB: W_out^T [1024][1024]
  bf16* qkb  = (bf16*)(ws + 16777216);            // 16 MB: QK bf16 [4096][2048]
  bf16* vtb  = (bf16*)(ws + 33554432);            //  8 MB: V^T bf16 [32*64][2048]
  bf16* attn = xb;                                //  reuse: xb dead after GEMM1

  k_convert_x<<<4096, 256, 0, stream>>>((const float4*)x, xb);
  k_transpose_w<<<dim3(96, 32), 256, 0, stream>>>(W_in, wti, 1024, 3072);
  k_transpose_w<<<dim3(32, 32), 256, 0, stream>>>(W_out, wto, 1024, 1024);
  k_gemm_bt<bf16, 1><<<dim3(24, 32), 256, 0, stream>>>(xb, wti, nullptr, qkb, vtb,
                                                       MROWS, D3, DIM);
  k_attn<<<1024, 256, 0, stream>>>(qkb, vtb, attn);
  k_gemm_bt<float, 0><<<dim3(8, 32), 256, 0, stream>>>(attn, wto, out, nullptr, nullptr,
                                                       MROWS, DIM, DIM);
}

// Round 3
// 193.906 us; speedup vs baseline: 1.4185x; 1.1304x over previous
//
#include <hip/hip_runtime.h>
#include <cstdint>
#include <cstddef>

// ---------- types ----------
typedef __bf16 bf16;
typedef bf16  bf16x4  __attribute__((ext_vector_type(4)));
typedef bf16  bf16x8  __attribute__((ext_vector_type(8)));
typedef float floatx4 __attribute__((ext_vector_type(4)));

// Problem constants (reference: B=2, S=2048, D=1024, H=16, Dh=64)
#define BATCH 2
#define SEQ   2048
#define DIM   1024
#define NH    16
#define DH    64
#define D3    3072
#define MROWS 4096   // BATCH*SEQ

// async global->LDS, 16B per lane; LDS dest must be wave-uniform base + lane*16
__device__ __forceinline__ void gld16(void* lds, const void* gptr) {
  __builtin_amdgcn_global_load_lds(
      (const __attribute__((address_space(1))) unsigned int*)gptr,
      (__attribute__((address_space(3))) unsigned int*)lds, 16, 0, 0);
}

// ---------- kernel 1: fp32 -> bf16 convert (x) ----------
__global__ __launch_bounds__(256) void k_convert_x(const float4* __restrict__ in,
                                                   bf16* __restrict__ out) {
  int i = blockIdx.x * 256 + threadIdx.x;     // 1048576 float4s total
  float4 v = in[i];
  bf16x4 o;
  o.x = (bf16)v.x; o.y = (bf16)v.y; o.z = (bf16)v.z; o.w = (bf16)v.w;
  *(bf16x4*)(out + (size_t)i * 4) = o;
}

// ---------- kernel 2: W[K][N] fp32 -> Wt[N][K] bf16 (32x32 LDS tiles) ----------
__global__ __launch_bounds__(256) void k_transpose_w(const float* __restrict__ W,
                                                     bf16* __restrict__ Wt,
                                                     int K, int N) {
  __shared__ float tile[32][33];
  int k0 = blockIdx.y * 32, n0 = blockIdx.x * 32;
  int tx = threadIdx.x & 31, ty = threadIdx.x >> 5;   // ty in [0,8)
#pragma unroll
  for (int i = 0; i < 4; i++)
    tile[ty + i * 8][tx] = W[(size_t)(k0 + ty + i * 8) * N + n0 + tx];
  __syncthreads();
#pragma unroll
  for (int i = 0; i < 4; i++)
    Wt[(size_t)(n0 + ty + i * 8) * K + k0 + tx] = (bf16)tile[tx][ty + i * 8];
}

// ---------- kernel 3: GEMM  C = A[M][K] * Bt[N][K]^T  (m97 structure) ----------
// MODE 0: plain C[M][N] (OutT). MODE 1: qkv-split epilogue:
//   cols <2048 -> qk[row][col] (stride 2048); cols >=2048 -> vt[bh*64+dh][s] (V transposed)
template <typename OutT, int MODE>
__global__ __launch_bounds__(256) void k_gemm_bt(const bf16* __restrict__ A,
                                                 const bf16* __restrict__ Bt,
                                                 OutT* __restrict__ C,
                                                 bf16* __restrict__ qk,
                                                 bf16* __restrict__ vt,
                                                 int M, int N, int K) {
  __shared__ __align__(16) bf16 As[128 * 32];
  __shared__ __align__(16) bf16 Bs[128 * 32];
  const int t = threadIdx.x, l = t & 63, w = t >> 6;
  const int wr = w >> 1, wc = w & 1;
  const int q = l >> 4, mm = l & 15;
  const int m0 = blockIdx.y * 128, n0 = blockIdx.x * 128;

  floatx4 acc[4][4] = {};

  for (int kt = 0; kt < K; kt += 32) {
    __syncthreads();
#pragma unroll
    for (int i = 0; i < 2; i++) {
      int c = t + i * 256;                 // 512 chunks of 16B per tile
      int row = c >> 2, col = (c & 3) * 8;
      gld16((char*)As + (size_t)c * 16, A  + (size_t)(m0 + row) * K + kt + col);
      gld16((char*)Bs + (size_t)c * 16, Bt + (size_t)(n0 + row) * K + kt + col);
    }
    __syncthreads();
    bf16x8 af[4], bfr[4];
#pragma unroll
    for (int mt = 0; mt < 4; mt++)
      af[mt] = *(const bf16x8*)(As + (size_t)(wr * 64 + mt * 16 + mm) * 32 + q * 8);
#pragma unroll
    for (int nt = 0; nt < 4; nt++)
      bfr[nt] = *(const bf16x8*)(Bs + (size_t)(wc * 64 + nt * 16 + mm) * 32 + q * 8);
#pragma unroll
    for (int mt = 0; mt < 4; mt++)
#pragma unroll
      for (int nt = 0; nt < 4; nt++)
        acc[mt][nt] = __builtin_amdgcn_mfma_f32_16x16x32_bf16(af[mt], bfr[nt],
                                                              acc[mt][nt], 0, 0, 0);
  }
  // epilogue: C/D layout col=lane&15, row=(lane>>4)*4+reg
#pragma unroll
  for (int mt = 0; mt < 4; mt++)
#pragma unroll
    for (int nt = 0; nt < 4; nt++)
#pragma unroll
      for (int r = 0; r < 4; r++) {
        int row = m0 + wr * 64 + mt * 16 + q * 4 + r;
        int col = n0 + wc * 64 + nt * 16 + mm;
        if (MODE == 0) {
          C[(size_t)row * N + col] = (OutT)acc[mt][nt][r];
        } else {
          if (n0 < 2048) {
            qk[(size_t)row * 2048 + col] = (bf16)acc[mt][nt][r];
          } else {
            int d = col - 2048;                  // 0..1023
            int hh = d >> 6, dh = d & 63;
            int bb = row >> 11, s = row & 2047;
            vt[((size_t)(bb * 16 + hh) * 64 + dh) * SEQ + s] = (bf16)acc[mt][nt][r];
          }
        }
      }
}

// ---------- kernel 4: causal flash attention (transposed dataflow, dbuf K/V) ----------
// 1024 blocks; snake task remap balances causal work assuming period-256 round-robin
// dispatch: CU-slot c gets qt = {31-j, 16+j, 15-j, j} (j=c>>5) -> 66 iters each.
// 4 waves, wave w owns q rows w*16..w*16+15. S^T = mfma(K,Q): lane owns q-row = lane&15.
__global__ __launch_bounds__(256) void k_attn(const bf16* __restrict__ qk,
                                              const bf16* __restrict__ vt,
                                              bf16* __restrict__ out) {
  const int bx = blockIdx.x;
  const int rr_ = bx >> 8, cc_ = bx & 255;
  const int tsk = (rr_ & 1) ? ((rr_ << 8) + 255 - cc_) : bx;
  const int qt = 31 - (tsk >> 5);
  const int bh = tsk & 31;
  const int b = bh >> 4, h = bh & 15;
  const int t = threadIdx.x, l = t & 63, w = t >> 6;
  const int q4 = l >> 4, mm = l & 15;

  // LDS: union{ Qs[2][64][32] (8192B, dead after qf load) ; Ps[4][16][72] (9216B) }
  //      Ks: 2 x [2][64][32] (2 x 8192B) ; Vs: 2 x [64][64] (2 x 8192B, XOR-swizzled)
  __shared__ __align__(16) char lds[9216 + 16384 + 16384];
  bf16* Qs = (bf16*)lds;                  // [2][64][32]
  bf16* Ps = (bf16*)lds;                  // [4][16][72]
  bf16* Ks = (bf16*)(lds + 9216);         // buf bp at +bp*4096 elems
  bf16* Vs = (bf16*)(lds + 9216 + 16384); // buf bp at +bp*4096 elems

  const size_t qkbase = (size_t)b * SEQ * 2048;
  const size_t vtbase = (size_t)bh * 64 * SEQ;

  // stage K (2x gld16) + V^T (2x gld16, XOR-swizzled 16B chunks) into buf kt&1
  auto stage = [&](int kt) {
    const int bp = kt & 1;
    int row = t >> 2, col = (t & 3) * 8;
#pragma unroll
    for (int i = 0; i < 2; i++)
      gld16((char*)(Ks + bp * 4096) + ((size_t)t + i * 256) * 16,
            qk + qkbase + (size_t)(kt * 64 + row) * 2048 + 1024 + h * 64 + i * 32 + col);
#pragma unroll
    for (int i = 0; i < 2; i++) {
      int c = t + i * 256;               // 512 chunks: row d = c>>3, chunk cc = c&7
      int vr = c >> 3, vc = c & 7;
      int src = vc ^ (vr & 7);
      gld16((char*)(Vs + bp * 4096) + (size_t)c * 16,
            vt + vtbase + (size_t)vr * SEQ + kt * 64 + src * 8);
    }
  };

  { // stage Q tile once (cols h*64 .. h*64+63, rows qt*64..+63)
    int row = t >> 2, col = (t & 3) * 8;
#pragma unroll
    for (int i = 0; i < 2; i++)
      gld16((char*)Qs + ((size_t)t + i * 256) * 16,
            qk + qkbase + (size_t)(qt * 64 + row) * 2048 + h * 64 + i * 32 + col);
  }
  stage(0);
  __syncthreads();                        // Q + stage(0) landed
  bf16x8 qf[2];
  qf[0] = *(const bf16x8*)(Qs + (size_t)(0 * 64 + w * 16 + mm) * 32 + q4 * 8);
  qf[1] = *(const bf16x8*)(Qs + (size_t)(1 * 64 + w * 16 + mm) * 32 + q4 * 8);
  // prescale by 1/sqrt(64) * log2(e): softmax runs in exp2 domain
#pragma unroll
  for (int i = 0; i < 2; i++)
#pragma unroll
    for (int j = 0; j < 8; j++)
      qf[i][j] = (bf16)((float)qf[i][j] * 0.18033688f);
  __syncthreads();                        // all waves read Q before Ps overwrites it

  float m_i = -__builtin_inff(), l_i = 0.f;
  floatx4 oaccT[4];                        // O^T: d = nt*16+q4*4+r, q-col = mm
#pragma unroll
  for (int nt = 0; nt < 4; nt++) { floatx4 z = {0.f, 0.f, 0.f, 0.f}; oaccT[nt] = z; }

  const int qloc = w * 16 + mm;            // this lane's q row within tile
  const int qrow = qt * 64 + qloc;

  for (int kt = 0; kt <= qt; kt++) {
    if (kt < qt) stage(kt + 1);            // in flight during this iter's compute
    const bf16* Kb = Ks + (kt & 1) * 4096;
    const bf16* Vb = Vs + (kt & 1) * 4096;

    // S^T tile: 64 k rows x 16 q cols per wave: mfma(A=K, B=Q)
    floatx4 sacc[4];
#pragma unroll
    for (int ct = 0; ct < 4; ct++) { floatx4 z = {0.f, 0.f, 0.f, 0.f}; sacc[ct] = z; }
#pragma unroll
    for (int ks = 0; ks < 2; ks++)
#pragma unroll
      for (int ct = 0; ct < 4; ct++) {
        bf16x8 kf = *(const bf16x8*)(Kb + (size_t)(ks * 64 + ct * 16 + mm) * 32 + q4 * 8);
        sacc[ct] = __builtin_amdgcn_mfma_f32_16x16x32_bf16(kf, qf[ks], sacc[ct], 0, 0, 0);
      }

    // per-lane: 16 scores (log2 units) for q=qrow at k = kt*64 + ct*16 + q4*4 + r
    float p[4][4];
    float mx = -__builtin_inff();
    if (kt == qt) {                        // diagonal tile: causal mask
#pragma unroll
      for (int ct = 0; ct < 4; ct++)
#pragma unroll
        for (int r = 0; r < 4; r++) {
          float sv = sacc[ct][r];
          if (ct * 16 + q4 * 4 + r > qloc) sv = -__builtin_inff();
          p[ct][r] = sv;
          mx = fmaxf(mx, sv);
        }
    } else {
#pragma unroll
      for (int ct = 0; ct < 4; ct++)
#pragma unroll
        for (int r = 0; r < 4; r++) {
          p[ct][r] = sacc[ct][r];
          mx = fmaxf(mx, sacc[ct][r]);
        }
    }
    mx = fmaxf(mx, __shfl_xor(mx, 16, 64));
    mx = fmaxf(mx, __shfl_xor(mx, 32, 64));

    float mnew = fmaxf(m_i, mx);
    float alpha = __builtin_amdgcn_exp2f(m_i - mnew);   // exp2(-inf - finite) = 0
    m_i = mnew;
    float rsum = 0.f;
#pragma unroll
    for (int ct = 0; ct < 4; ct++)
#pragma unroll
      for (int r = 0; r < 4; r++) {
        float e = __builtin_amdgcn_exp2f(p[ct][r] - m_i);
        p[ct][r] = e;
        rsum += e;
      }
    rsum += __shfl_xor(rsum, 16, 64);
    rsum += __shfl_xor(rsum, 32, 64);
    l_i = l_i * alpha + rsum;
#pragma unroll
    for (int nt = 0; nt < 4; nt++)
#pragma unroll
      for (int r = 0; r < 4; r++) oaccT[nt][r] *= alpha;

    // P^T (C-layout) -> A/B-layout: lane writes its 4 consecutive k per ct (b64 stores)
#pragma unroll
    for (int ct = 0; ct < 4; ct++) {
      bf16x4 pk;
#pragma unroll
      for (int r = 0; r < 4; r++) pk[r] = (bf16)p[ct][r];
      *(bf16x4*)(Ps + (size_t)(w * 16 + mm) * 72 + ct * 16 + q4 * 4) = pk;
    }

    // O^T += mfma(A=V^T, B=P)
#pragma unroll
    for (int ks = 0; ks < 2; ks++) {
      bf16x8 pf = *(const bf16x8*)(Ps + (size_t)(w * 16 + mm) * 72 + ks * 32 + q4 * 8);
#pragma unroll
      for (int nt = 0; nt < 4; nt++) {
        int d = nt * 16 + mm;
        int chunk = (ks * 4 + q4) ^ (mm & 7);    // undo staging swizzle (d&7 == mm&7)
        bf16x8 vf = *(const bf16x8*)(Vb + (size_t)d * 64 + chunk * 8);
        oaccT[nt] = __builtin_amdgcn_mfma_f32_16x16x32_bf16(vf, pf, oaccT[nt], 0, 0, 0);
      }
    }

    if (kt < qt) __syncthreads();          // drains stage(kt+1); guards bufs + Ps reuse
  }

  // epilogue: lane owns one q row; normalize and store 4x bf16x4
  float inv = 1.0f / l_i;
  bf16* orow = out + ((size_t)b * SEQ + qrow) * DIM + h * 64;
#pragma unroll
  for (int nt = 0; nt < 4; nt++) {
    bf16x4 o4;
#pragma unroll
    for (int r = 0; r < 4; r++) o4[r] = (bf16)(oaccT[nt][r] * inv);
    *(bf16x4*)(orow + nt * 16 + q4 * 4) = o4;
  }
}

// ---------- launch ----------
extern "C" void kernel_launch(void* const* d_in, const int* in_sizes, int n_in,
                              void* d_out, int out_size, void* d_ws, size_t ws_size,
                              hipStream_t stream) {
  const float* x     = (const float*)d_in[0];   // [2,2048,1024]
  const float* W_in  = (const float*)d_in[1];   // [1024,3072]
  const float* W_out = (const float*)d_in[2];   // [1024,1024]
  float* out = (float*)d_out;                   // [2,2048,1024]

  char* ws = (char*)d_ws;
  bf16* xb   = (bf16*)(ws);                       //  8 MB: x bf16 [4096][1024] (reused: attn out)
  bf16* wti  = (bf16*)(ws + 8388608);             //  6 MB: W_in^T  [3072][1024]
  bf16* wto  = (bf16*)(ws + 14680064);            //  2 MB: W_out^T [1024][1024]
  bf16* qkb  = (bf16*)(ws + 16777216);            // 16 MB: QK bf16 [4096][2048]
  bf16* vtb  = (bf16*)(ws + 33554432);            //  8 MB: V^T bf16 [32*64][2048]
  bf16* attn = xb;                                //  reuse: xb dead after GEMM1

  k_convert_x<<<4096, 256, 0, stream>>>((const float4*)x, xb);
  k_transpose_w<<<dim3(96, 32), 256, 0, stream>>>(W_in, wti, 1024, 3072);
  k_transpose_w<<<dim3(32, 32), 256, 0, stream>>>(W_out, wto, 1024, 1024);
  k_gemm_bt<bf16, 1><<<dim3(24, 32), 256, 0, stream>>>(xb, wti, nullptr, qkb, vtb,
                                                       MROWS, D3, DIM);
  k_attn<<<1024, 256, 0, stream>>>(qkb, vtb, attn);
  k_gemm_bt<float, 0><<<dim3(8, 32), 256, 0, stream>>>(attn, wto, out, nullptr, nullptr,
                                                       MROWS, DIM, DIM);
}